// Round 1
// baseline (1145.093 us; speedup 1.0000x reference)
//
#include <hip/hip_runtime.h>

#define N_NODES 20000
#define E_EDGES 640000
#define F_DIM 128
#define RBF_DIM 64
#define T_TYPES 5
#define H_HEADS 8
#define DH_DIM 16

__device__ __forceinline__ float silu_f(float x) { return x / (1.0f + __expf(-x)); }

// ---------------- xl = x @ lin1_w^T ----------------
__global__ __launch_bounds__(128) void lin1_kernel(const float* __restrict__ x,
                                                   const float* __restrict__ w,
                                                   float* __restrict__ xl) {
  __shared__ float xs[8 * 128];
  int tid = threadIdx.x;
  int n0 = blockIdx.x * 8;
  const float4* xg = (const float4*)(x + (size_t)n0 * 128);
  float4* xs4 = (float4*)xs;
  for (int i = tid; i < 256; i += 128) xs4[i] = xg[i];
  __syncthreads();
  int f = tid;
  float acc[8] = {};
  const float4* w4 = (const float4*)(w + (size_t)f * 128);
  for (int j4 = 0; j4 < 32; ++j4) {
    float4 wv = w4[j4];
#pragma unroll
    for (int n = 0; n < 8; ++n) {
      float4 xv = xs4[n * 32 + j4];
      acc[n] += wv.x * xv.x + wv.y * xv.y + wv.z * xv.z + wv.w * xv.w;
    }
  }
  for (int n = 0; n < 8; ++n) xl[(size_t)(n0 + n) * 128 + f] = acc[n];
}

// ---------------- per-edge filter net + scatter ----------------
__global__ __launch_bounds__(256) void edge_kernel(
    const float* __restrict__ edge_attr, const int* __restrict__ srcp,
    const int* __restrict__ dstp, const float* __restrict__ ewp,
    const int* __restrict__ z, const float* __restrict__ w1,
    const float* __restrict__ b1, const float* __restrict__ w2,
    const float* __restrict__ b2, const float* __restrict__ xl,
    float* __restrict__ y, float* __restrict__ cnt) {
  __shared__ float ea[32 * 64];
  __shared__ float hs[32 * 128];
  __shared__ float sC[32];
  __shared__ int sseg[32];
  __shared__ int ssrc[32];
  int tid = threadIdx.x;
  int e0 = blockIdx.x * 32;

  const float4* eag = (const float4*)(edge_attr + (size_t)e0 * 64);
  float4* ea4 = (float4*)ea;
  for (int i = tid; i < 512; i += 256) ea4[i] = eag[i];
  if (tid < 32) {
    int e = e0 + tid;
    int s = srcp[e];
    ssrc[tid] = s;
    int sg = dstp[e] * T_TYPES + z[s];
    sseg[tid] = sg;
    float wdist = ewp[e];
    float c = 0.5f * (__cosf(wdist * 0.6283185307179586f) + 1.0f);
    sC[tid] = (wdist < 5.0f) ? c : 0.0f;
    cnt[sg] = 1.0f;  // idempotent presence mark
  }
  __syncthreads();

  // h = silu(ea @ w1^T + b1)   [32][128]
  {
    int j = tid & 127, g = tid >> 7;
    float4 w1r[16];
    const float4* w1g = (const float4*)(w1 + (size_t)j * 64);
#pragma unroll
    for (int r = 0; r < 16; ++r) w1r[r] = w1g[r];
    float bb = b1[j];
    for (int e = g; e < 32; e += 2) {
      float acc = bb;
#pragma unroll
      for (int r = 0; r < 16; ++r) {
        float4 a4 = ea4[e * 16 + r];
        acc += w1r[r].x * a4.x + w1r[r].y * a4.y + w1r[r].z * a4.z + w1r[r].w * a4.w;
      }
      hs[e * 128 + j] = silu_f(acc);
    }
  }
  __syncthreads();

  // W = h @ w2^T + b2, msg = xl[src]*W*C, scatter-add
  {
    int f = tid & 127, g = tid >> 7;
    float acc[16] = {};
    const float4* w2g = (const float4*)(w2 + (size_t)f * 128);
    const float4* h4 = (const float4*)hs;
    for (int j4 = 0; j4 < 32; ++j4) {
      float4 wv = w2g[j4];
#pragma unroll
      for (int ee = 0; ee < 16; ++ee) {
        int e = 2 * ee + g;
        float4 hv = h4[e * 32 + j4];
        acc[ee] += wv.x * hv.x + wv.y * hv.y + wv.z * hv.z + wv.w * hv.w;
      }
    }
    float bb = b2[f];
#pragma unroll
    for (int ee = 0; ee < 16; ++ee) {
      int e = 2 * ee + g;
      float W = (acc[ee] + bb) * sC[e];
      float msg = xl[(size_t)ssrc[e] * 128 + f] * W;
      atomicAdd(&y[(size_t)sseg[e] * 128 + f], msg);
    }
  }
}

// ---------------- per-node qkv + attention + slot-sum ----------------
__global__ __launch_bounds__(256) void attn_kernel(
    const float* __restrict__ y, const float* __restrict__ cnt,
    const float* __restrict__ qw, const float* __restrict__ qb,
    const float* __restrict__ kw, const float* __restrict__ kb,
    const float* __restrict__ vw, const float* __restrict__ vb,
    float* __restrict__ sout) {
  __shared__ float yq[40 * 128];  // holds y, later overwritten with q
  __shared__ float kk[40 * 128];
  __shared__ float vv[40 * 128];
  __shared__ float pmv[40];
  __shared__ float aa[8 * 8 * 5];  // [node][head][j]
  int tid = threadIdx.x;
  int n0 = blockIdx.x * 8;

  const float4* yg = (const float4*)(y + (size_t)n0 * T_TYPES * 128);
  float4* y4 = (float4*)yq;
  for (int i = tid; i < 40 * 32; i += 256) y4[i] = yg[i];
  if (tid < 40) pmv[tid] = (cnt[(size_t)n0 * T_TYPES + tid] > 0.0f) ? 1.0f : 0.0f;
  __syncthreads();

  int f = tid & 127, g = tid >> 7;

  // k = y @ kw^T + kb
  {
    const float4* wg = (const float4*)(kw + (size_t)f * 128);
    float acc[20] = {};
    for (int j4 = 0; j4 < 32; ++j4) {
      float4 wv = wg[j4];
#pragma unroll
      for (int r = 0; r < 20; ++r) {
        float4 yv = y4[(g * 20 + r) * 32 + j4];
        acc[r] += wv.x * yv.x + wv.y * yv.y + wv.z * yv.z + wv.w * yv.w;
      }
    }
    float bb = kb[f];
    for (int r = 0; r < 20; ++r) kk[(g * 20 + r) * 128 + f] = acc[r] + bb;
  }
  // v = y @ vw^T + vb
  {
    const float4* wg = (const float4*)(vw + (size_t)f * 128);
    float acc[20] = {};
    for (int j4 = 0; j4 < 32; ++j4) {
      float4 wv = wg[j4];
#pragma unroll
      for (int r = 0; r < 20; ++r) {
        float4 yv = y4[(g * 20 + r) * 32 + j4];
        acc[r] += wv.x * yv.x + wv.y * yv.y + wv.z * yv.z + wv.w * yv.w;
      }
    }
    float bb = vb[f];
    for (int r = 0; r < 20; ++r) vv[(g * 20 + r) * 128 + f] = acc[r] + bb;
  }
  // q = y @ qw^T + qb  (into registers, then overwrite y-space)
  {
    const float4* wg = (const float4*)(qw + (size_t)f * 128);
    float acc[20] = {};
    for (int j4 = 0; j4 < 32; ++j4) {
      float4 wv = wg[j4];
#pragma unroll
      for (int r = 0; r < 20; ++r) {
        float4 yv = y4[(g * 20 + r) * 32 + j4];
        acc[r] += wv.x * yv.x + wv.y * yv.y + wv.z * yv.z + wv.w * yv.w;
      }
    }
    float bb = qb[f];
    __syncthreads();  // all reads of y done
    for (int r = 0; r < 20; ++r) yq[(g * 20 + r) * 128 + f] = acc[r] + bb;
  }
  __syncthreads();

  // a[n][h][j] = pm_j * sum_i pm_i * silu(q_i . k_j)
  for (int idx = tid; idx < 320; idx += 256) {
    int n = idx / 40;
    int rem = idx % 40;
    int h = rem / 5;
    int j = rem % 5;
    const float* qp = yq + (n * 5) * 128 + h * 16;
    const float* kp = kk + (n * 5 + j) * 128 + h * 16;
    float acc = 0.0f;
    for (int i = 0; i < 5; ++i) {
      float d = 0.0f;
#pragma unroll
      for (int dd = 0; dd < 16; ++dd) d += qp[i * 128 + dd] * kp[dd];
      acc += pmv[n * 5 + i] * silu_f(d);
    }
    aa[idx] = acc * pmv[n * 5 + j];
  }
  __syncthreads();

  // s[n][f] = sum_j a[n][h(f)][j] * v[n][j][f]
  {
    int h = f >> 4;
    for (int nn = 0; nn < 4; ++nn) {
      int n = g * 4 + nn;
      float acc = 0.0f;
#pragma unroll
      for (int j = 0; j < 5; ++j) acc += aa[n * 40 + h * 5 + j] * vv[(n * 5 + j) * 128 + f];
      sout[(size_t)(n0 + n) * 128 + f] = acc;
    }
  }
}

// ---------------- out = silu((s@o1^T + npm*o1_b) @ o2^T + o2_b) ----------------
__global__ __launch_bounds__(128) void out_kernel(
    const float* __restrict__ sbufg, const float* __restrict__ cnt,
    const float* __restrict__ o1w, const float* __restrict__ o1b,
    const float* __restrict__ o2w, const float* __restrict__ o2b,
    float* __restrict__ outp) {
  __shared__ float sb[8 * 128];
  __shared__ float t1[8 * 128];
  __shared__ float npm[8];
  int tid = threadIdx.x;
  int n0 = blockIdx.x * 8;
  const float4* sg4 = (const float4*)(sbufg + (size_t)n0 * 128);
  float4* sb4 = (float4*)sb;
  for (int i = tid; i < 256; i += 128) sb4[i] = sg4[i];
  if (tid < 8) {
    float s = 0.0f;
    for (int t = 0; t < T_TYPES; ++t)
      s += (cnt[(size_t)(n0 + tid) * T_TYPES + t] > 0.0f) ? 1.0f : 0.0f;
    npm[tid] = s;
  }
  __syncthreads();
  int f = tid;
  {
    const float4* wg = (const float4*)(o1w + (size_t)f * 128);
    float acc[8] = {};
    for (int j4 = 0; j4 < 32; ++j4) {
      float4 wv = wg[j4];
#pragma unroll
      for (int n = 0; n < 8; ++n) {
        float4 sv = sb4[n * 32 + j4];
        acc[n] += wv.x * sv.x + wv.y * sv.y + wv.z * sv.z + wv.w * sv.w;
      }
    }
    float bb = o1b[f];
    for (int n = 0; n < 8; ++n) t1[n * 128 + f] = acc[n] + npm[n] * bb;
  }
  __syncthreads();
  {
    const float4* wg = (const float4*)(o2w + (size_t)f * 128);
    const float4* t14 = (const float4*)t1;
    float acc[8] = {};
    for (int j4 = 0; j4 < 32; ++j4) {
      float4 wv = wg[j4];
#pragma unroll
      for (int n = 0; n < 8; ++n) {
        float4 tv = t14[n * 32 + j4];
        acc[n] += wv.x * tv.x + wv.y * tv.y + wv.z * tv.z + wv.w * tv.w;
      }
    }
    float bb = o2b[f];
    for (int n = 0; n < 8; ++n) outp[(size_t)(n0 + n) * 128 + f] = silu_f(acc[n] + bb);
  }
}

extern "C" void kernel_launch(void* const* d_in, const int* in_sizes, int n_in,
                              void* d_out, int out_size, void* d_ws, size_t ws_size,
                              hipStream_t stream) {
  const float* x = (const float*)d_in[0];
  const int* z = (const int*)d_in[1];
  const int* ei = (const int*)d_in[2];
  const float* ew = (const float*)d_in[3];
  const float* ea = (const float*)d_in[4];
  const float* lin1_w = (const float*)d_in[5];
  const float* fw1 = (const float*)d_in[6];
  const float* fb1 = (const float*)d_in[7];
  const float* fw2 = (const float*)d_in[8];
  const float* fb2 = (const float*)d_in[9];
  const float* qw = (const float*)d_in[10];
  const float* qb = (const float*)d_in[11];
  const float* kw = (const float*)d_in[12];
  const float* kb = (const float*)d_in[13];
  const float* vw = (const float*)d_in[14];
  const float* vb = (const float*)d_in[15];
  const float* o1w = (const float*)d_in[16];
  const float* o1b = (const float*)d_in[17];
  const float* o2w = (const float*)d_in[18];
  const float* o2b = (const float*)d_in[19];
  float* outp = (float*)d_out;
  float* ws = (float*)d_ws;

  float* xl = ws;                                      // N*F
  float* y = xl + (size_t)N_NODES * F_DIM;             // N*T*F
  float* cnt = y + (size_t)N_NODES * T_TYPES * F_DIM;  // N*T
  float* sbuf = cnt + (size_t)N_NODES * T_TYPES;       // N*F

  const int* srcp = ei;
  const int* dstp = ei + E_EDGES;

  hipMemsetAsync(y, 0,
                 (size_t)(N_NODES * T_TYPES * F_DIM + N_NODES * T_TYPES) * sizeof(float),
                 stream);
  lin1_kernel<<<N_NODES / 8, 128, 0, stream>>>(x, lin1_w, xl);
  edge_kernel<<<E_EDGES / 32, 256, 0, stream>>>(ea, srcp, dstp, ew, z, fw1, fb1,
                                                fw2, fb2, xl, y, cnt);
  attn_kernel<<<N_NODES / 8, 256, 0, stream>>>(y, cnt, qw, qb, kw, kb, vw, vb, sbuf);
  out_kernel<<<N_NODES / 8, 128, 0, stream>>>(sbuf, cnt, o1w, o1b, o2w, o2b, outp);
}

// Round 2
// 670.170 us; speedup vs baseline: 1.7087x; 1.7087x over previous
//
#include <hip/hip_runtime.h>

#define N_NODES 20000
#define E_EDGES 640000
#define F_DIM 128
#define RBF_DIM 64
#define T_TYPES 5

typedef __attribute__((ext_vector_type(8))) short short8;
typedef __attribute__((ext_vector_type(4))) float f32x4;

__device__ __forceinline__ float silu_f(float x) { return x / (1.0f + __expf(-x)); }

__device__ __forceinline__ ushort f2bf(float f) {
  unsigned u = __float_as_uint(f);
  u += 0x7fffu + ((u >> 16) & 1u);
  return (ushort)(u >> 16);
}

// ---------------- weight prep: fp32 -> bf16 ----------------
__global__ __launch_bounds__(256) void prep_kernel(const float* __restrict__ w1,
                                                   const float* __restrict__ w2,
                                                   ushort* __restrict__ w1b,
                                                   ushort* __restrict__ w2b) {
  int i = blockIdx.x * 256 + threadIdx.x;
  if (i < F_DIM * RBF_DIM) w1b[i] = f2bf(w1[i]);
  if (i < F_DIM * F_DIM) w2b[i] = f2bf(w2[i]);
}

// ---------------- xl = x @ lin1_w^T ----------------
__global__ __launch_bounds__(128) void lin1_kernel(const float* __restrict__ x,
                                                   const float* __restrict__ w,
                                                   float* __restrict__ xl) {
  __shared__ float xs[8 * 128];
  int tid = threadIdx.x;
  int n0 = blockIdx.x * 8;
  const float4* xg = (const float4*)(x + (size_t)n0 * 128);
  float4* xs4 = (float4*)xs;
  for (int i = tid; i < 256; i += 128) xs4[i] = xg[i];
  __syncthreads();
  int f = tid;
  float acc[8] = {};
  const float4* w4 = (const float4*)(w + (size_t)f * 128);
  for (int j4 = 0; j4 < 32; ++j4) {
    float4 wv = w4[j4];
#pragma unroll
    for (int n = 0; n < 8; ++n) {
      float4 xv = xs4[n * 32 + j4];
      acc[n] += wv.x * xv.x + wv.y * xv.y + wv.z * xv.z + wv.w * xv.w;
    }
  }
  for (int n = 0; n < 8; ++n) xl[(size_t)(n0 + n) * 128 + f] = acc[n];
}

// ---------------- per-edge filter net (MFMA) + scatter ----------------
// Tile: 128 edges x 128 features, 4 waves in 2x2.
// GEMM1: h = silu(EA @ w1^T + b1)  (K=64, A from global fp32->bf16, B=w1b global)
// GEMM2: W = h @ w2^T + b2         (K=128, A from swizzled LDS, B=w2b global)
// epilogue: msg = xl[src] * W * C, atomicAdd into y slot grid.
__global__ __launch_bounds__(256, 3) void edge_mfma_kernel(
    const float* __restrict__ edge_attr, const int* __restrict__ srcp,
    const int* __restrict__ dstp, const float* __restrict__ ewp,
    const int* __restrict__ z, const ushort* __restrict__ w1b,
    const float* __restrict__ b1, const ushort* __restrict__ w2b,
    const float* __restrict__ b2, const float* __restrict__ xl,
    float* __restrict__ y, float* __restrict__ cnt) {
  __shared__ ushort hs[128 * 128];  // bf16 h, XOR-swizzled rows (stride 256B)
  __shared__ float sC[128];
  __shared__ int ssrc[128];
  __shared__ int sseg[128];
  __shared__ float sb1[128];
  __shared__ float sb2[128];

  const int tid = threadIdx.x;
  const int e0 = blockIdx.x * 128;
  const int lane = tid & 63;
  const int w = tid >> 6;
  const int wm = w >> 1, wn = w & 1;
  const int lr = lane & 15, lh = lane >> 4;

  if (tid < 128) {
    int e = e0 + tid;
    int s = srcp[e];
    ssrc[tid] = s;
    int sg = dstp[e] * T_TYPES + z[s];
    sseg[tid] = sg;
    float wd = ewp[e];
    float c = 0.5f * (__cosf(wd * 0.6283185307179586f) + 1.0f);
    sC[tid] = (wd < 5.0f) ? c : 0.0f;
    cnt[sg] = 1.0f;  // idempotent presence mark
    sb1[tid] = b1[tid];
    sb2[tid] = b2[tid];
  }
  __syncthreads();

  // ---- GEMM1: h = silu(EA @ w1^T + b1), write bf16 into swizzled LDS ----
  {
    f32x4 acc[4][4] = {};  // [fm][fc]
#pragma unroll
    for (int ks = 0; ks < 2; ++ks) {
      const int k0 = ks * 32;
      short8 af[4], bfr[4];
#pragma unroll
      for (int fm = 0; fm < 4; ++fm) {
        const float* ap =
            edge_attr + (size_t)(e0 + wm * 64 + fm * 16 + lr) * 64 + k0 + lh * 8;
        float4 a0 = *(const float4*)ap;
        float4 a1 = *(const float4*)(ap + 4);
        short8 t;
        t[0] = (short)f2bf(a0.x); t[1] = (short)f2bf(a0.y);
        t[2] = (short)f2bf(a0.z); t[3] = (short)f2bf(a0.w);
        t[4] = (short)f2bf(a1.x); t[5] = (short)f2bf(a1.y);
        t[6] = (short)f2bf(a1.z); t[7] = (short)f2bf(a1.w);
        af[fm] = t;
      }
#pragma unroll
      for (int fc = 0; fc < 4; ++fc)
        bfr[fc] = *(const short8*)(w1b + (size_t)(wn * 64 + fc * 16 + lr) * 64 +
                                   k0 + lh * 8);
#pragma unroll
      for (int fm = 0; fm < 4; ++fm)
#pragma unroll
        for (int fc = 0; fc < 4; ++fc)
          acc[fm][fc] = __builtin_amdgcn_mfma_f32_16x16x32_bf16(
              af[fm], bfr[fc], acc[fm][fc], 0, 0, 0);
    }
    // epilogue: silu + bias, store to swizzled LDS
#pragma unroll
    for (int fm = 0; fm < 4; ++fm) {
#pragma unroll
      for (int fc = 0; fc < 4; ++fc) {
#pragma unroll
        for (int r = 0; r < 4; ++r) {
          int ml = wm * 64 + fm * 16 + lh * 4 + r;
          int n = wn * 64 + fc * 16 + lr;
          float hv = silu_f(acc[fm][fc][r] + sb1[n]);
          int byte_in_row = (n * 2) ^ ((ml & 7) << 4);
          hs[(ml * 256 + byte_in_row) >> 1] = f2bf(hv);
        }
      }
    }
  }
  __syncthreads();

  // ---- GEMM2: W = h @ w2^T + b2, fused epilogue ----
  f32x4 acc2[4][4] = {};
#pragma unroll
  for (int ks = 0; ks < 4; ++ks) {
    const int k0 = ks * 32;
    short8 af[4], bfr[4];
#pragma unroll
    for (int fm = 0; fm < 4; ++fm) {
      int ml = wm * 64 + fm * 16 + lr;
      int byte_in_row = (k0 * 2 + lh * 16) ^ ((ml & 7) << 4);
      af[fm] = *(const short8*)&hs[(ml * 256 + byte_in_row) >> 1];
    }
#pragma unroll
    for (int fc = 0; fc < 4; ++fc)
      bfr[fc] = *(const short8*)(w2b + (size_t)(wn * 64 + fc * 16 + lr) * 128 +
                                 k0 + lh * 8);
#pragma unroll
    for (int fm = 0; fm < 4; ++fm)
#pragma unroll
      for (int fc = 0; fc < 4; ++fc)
        acc2[fm][fc] = __builtin_amdgcn_mfma_f32_16x16x32_bf16(
            af[fm], bfr[fc], acc2[fm][fc], 0, 0, 0);
  }

#pragma unroll
  for (int fm = 0; fm < 4; ++fm) {
#pragma unroll
    for (int r = 0; r < 4; ++r) {
      int ml = wm * 64 + fm * 16 + lh * 4 + r;
      float c = sC[ml];
      int s = ssrc[ml];
      int sg = sseg[ml];
      const float* xlr = xl + (size_t)s * 128;
      float* yr = y + (size_t)sg * 128;
#pragma unroll
      for (int fc = 0; fc < 4; ++fc) {
        int n = wn * 64 + fc * 16 + lr;
        float val = (acc2[fm][fc][r] + sb2[n]) * c * xlr[n];
        atomicAdd(&yr[n], val);
      }
    }
  }
}

// ---------------- per-node qkv + attention + slot-sum ----------------
__global__ __launch_bounds__(256) void attn_kernel(
    const float* __restrict__ y, const float* __restrict__ cnt,
    const float* __restrict__ qw, const float* __restrict__ qb,
    const float* __restrict__ kw, const float* __restrict__ kb,
    const float* __restrict__ vw, const float* __restrict__ vb,
    float* __restrict__ sout) {
  __shared__ float yq[40 * 128];  // holds y, later overwritten with q
  __shared__ float kk[40 * 128];
  __shared__ float vv[40 * 128];
  __shared__ float pmv[40];
  __shared__ float aa[8 * 8 * 5];  // [node][head][j]
  int tid = threadIdx.x;
  int n0 = blockIdx.x * 8;

  const float4* yg = (const float4*)(y + (size_t)n0 * T_TYPES * 128);
  float4* y4 = (float4*)yq;
  for (int i = tid; i < 40 * 32; i += 256) y4[i] = yg[i];
  if (tid < 40) pmv[tid] = (cnt[(size_t)n0 * T_TYPES + tid] > 0.0f) ? 1.0f : 0.0f;
  __syncthreads();

  int f = tid & 127, g = tid >> 7;

  {
    const float4* wg = (const float4*)(kw + (size_t)f * 128);
    float acc[20] = {};
    for (int j4 = 0; j4 < 32; ++j4) {
      float4 wv = wg[j4];
#pragma unroll
      for (int r = 0; r < 20; ++r) {
        float4 yv = y4[(g * 20 + r) * 32 + j4];
        acc[r] += wv.x * yv.x + wv.y * yv.y + wv.z * yv.z + wv.w * yv.w;
      }
    }
    float bb = kb[f];
    for (int r = 0; r < 20; ++r) kk[(g * 20 + r) * 128 + f] = acc[r] + bb;
  }
  {
    const float4* wg = (const float4*)(vw + (size_t)f * 128);
    float acc[20] = {};
    for (int j4 = 0; j4 < 32; ++j4) {
      float4 wv = wg[j4];
#pragma unroll
      for (int r = 0; r < 20; ++r) {
        float4 yv = y4[(g * 20 + r) * 32 + j4];
        acc[r] += wv.x * yv.x + wv.y * yv.y + wv.z * yv.z + wv.w * yv.w;
      }
    }
    float bb = vb[f];
    for (int r = 0; r < 20; ++r) vv[(g * 20 + r) * 128 + f] = acc[r] + bb;
  }
  {
    const float4* wg = (const float4*)(qw + (size_t)f * 128);
    float acc[20] = {};
    for (int j4 = 0; j4 < 32; ++j4) {
      float4 wv = wg[j4];
#pragma unroll
      for (int r = 0; r < 20; ++r) {
        float4 yv = y4[(g * 20 + r) * 32 + j4];
        acc[r] += wv.x * yv.x + wv.y * yv.y + wv.z * yv.z + wv.w * yv.w;
      }
    }
    float bb = qb[f];
    __syncthreads();  // all reads of y done
    for (int r = 0; r < 20; ++r) yq[(g * 20 + r) * 128 + f] = acc[r] + bb;
  }
  __syncthreads();

  for (int idx = tid; idx < 320; idx += 256) {
    int n = idx / 40;
    int rem = idx % 40;
    int h = rem / 5;
    int j = rem % 5;
    const float* qp = yq + (n * 5) * 128 + h * 16;
    const float* kp = kk + (n * 5 + j) * 128 + h * 16;
    float acc = 0.0f;
    for (int i = 0; i < 5; ++i) {
      float d = 0.0f;
#pragma unroll
      for (int dd = 0; dd < 16; ++dd) d += qp[i * 128 + dd] * kp[dd];
      acc += pmv[n * 5 + i] * silu_f(d);
    }
    aa[idx] = acc * pmv[n * 5 + j];
  }
  __syncthreads();

  {
    int h = f >> 4;
    for (int nn = 0; nn < 4; ++nn) {
      int n = g * 4 + nn;
      float acc = 0.0f;
#pragma unroll
      for (int j = 0; j < 5; ++j)
        acc += aa[n * 40 + h * 5 + j] * vv[(n * 5 + j) * 128 + f];
      sout[(size_t)(n0 + n) * 128 + f] = acc;
    }
  }
}

// ---------------- out = silu((s@o1^T + npm*o1_b) @ o2^T + o2_b) ----------------
__global__ __launch_bounds__(128) void out_kernel(
    const float* __restrict__ sbufg, const float* __restrict__ cnt,
    const float* __restrict__ o1w, const float* __restrict__ o1b,
    const float* __restrict__ o2w, const float* __restrict__ o2b,
    float* __restrict__ outp) {
  __shared__ float sb[8 * 128];
  __shared__ float t1[8 * 128];
  __shared__ float npm[8];
  int tid = threadIdx.x;
  int n0 = blockIdx.x * 8;
  const float4* sg4 = (const float4*)(sbufg + (size_t)n0 * 128);
  float4* sb4 = (float4*)sb;
  for (int i = tid; i < 256; i += 128) sb4[i] = sg4[i];
  if (tid < 8) {
    float s = 0.0f;
    for (int t = 0; t < T_TYPES; ++t)
      s += (cnt[(size_t)(n0 + tid) * T_TYPES + t] > 0.0f) ? 1.0f : 0.0f;
    npm[tid] = s;
  }
  __syncthreads();
  int f = tid;
  {
    const float4* wg = (const float4*)(o1w + (size_t)f * 128);
    float acc[8] = {};
    for (int j4 = 0; j4 < 32; ++j4) {
      float4 wv = wg[j4];
#pragma unroll
      for (int n = 0; n < 8; ++n) {
        float4 sv = sb4[n * 32 + j4];
        acc[n] += wv.x * sv.x + wv.y * sv.y + wv.z * sv.z + wv.w * sv.w;
      }
    }
    float bb = o1b[f];
    for (int n = 0; n < 8; ++n) t1[n * 128 + f] = acc[n] + npm[n] * bb;
  }
  __syncthreads();
  {
    const float4* wg = (const float4*)(o2w + (size_t)f * 128);
    const float4* t14 = (const float4*)t1;
    float acc[8] = {};
    for (int j4 = 0; j4 < 32; ++j4) {
      float4 wv = wg[j4];
#pragma unroll
      for (int n = 0; n < 8; ++n) {
        float4 tv = t14[n * 32 + j4];
        acc[n] += wv.x * tv.x + wv.y * tv.y + wv.z * tv.z + wv.w * tv.w;
      }
    }
    float bb = o2b[f];
    for (int n = 0; n < 8; ++n) outp[(size_t)(n0 + n) * 128 + f] = silu_f(acc[n] + bb);
  }
}

extern "C" void kernel_launch(void* const* d_in, const int* in_sizes, int n_in,
                              void* d_out, int out_size, void* d_ws, size_t ws_size,
                              hipStream_t stream) {
  const float* x = (const float*)d_in[0];
  const int* z = (const int*)d_in[1];
  const int* ei = (const int*)d_in[2];
  const float* ew = (const float*)d_in[3];
  const float* ea = (const float*)d_in[4];
  const float* lin1_w = (const float*)d_in[5];
  const float* fw1 = (const float*)d_in[6];
  const float* fb1 = (const float*)d_in[7];
  const float* fw2 = (const float*)d_in[8];
  const float* fb2 = (const float*)d_in[9];
  const float* qw = (const float*)d_in[10];
  const float* qb = (const float*)d_in[11];
  const float* kw = (const float*)d_in[12];
  const float* kb = (const float*)d_in[13];
  const float* vw = (const float*)d_in[14];
  const float* vb = (const float*)d_in[15];
  const float* o1w = (const float*)d_in[16];
  const float* o1b = (const float*)d_in[17];
  const float* o2w = (const float*)d_in[18];
  const float* o2b = (const float*)d_in[19];
  float* outp = (float*)d_out;
  float* ws = (float*)d_ws;

  float* xl = ws;                                      // N*F
  float* y = xl + (size_t)N_NODES * F_DIM;             // N*T*F
  float* cnt = y + (size_t)N_NODES * T_TYPES * F_DIM;  // N*T
  float* sbuf = cnt + (size_t)N_NODES * T_TYPES;       // N*F
  ushort* w1b = (ushort*)(sbuf + (size_t)N_NODES * F_DIM);
  ushort* w2b = w1b + F_DIM * RBF_DIM;

  const int* srcp = ei;
  const int* dstp = ei + E_EDGES;

  hipMemsetAsync(y, 0,
                 (size_t)(N_NODES * T_TYPES * F_DIM + N_NODES * T_TYPES) * sizeof(float),
                 stream);
  prep_kernel<<<64, 256, 0, stream>>>(fw1, fw2, w1b, w2b);
  lin1_kernel<<<N_NODES / 8, 128, 0, stream>>>(x, lin1_w, xl);
  edge_mfma_kernel<<<E_EDGES / 128, 256, 0, stream>>>(ea, srcp, dstp, ew, z, w1b,
                                                      fb1, w2b, fb2, xl, y, cnt);
  attn_kernel<<<N_NODES / 8, 256, 0, stream>>>(y, cnt, qw, qb, kw, kb, vw, vb, sbuf);
  out_kernel<<<N_NODES / 8, 128, 0, stream>>>(sbuf, cnt, o1w, o1b, o2w, o2b, outp);
}

// Round 3
// 368.436 us; speedup vs baseline: 3.1080x; 1.8190x over previous
//
#include <hip/hip_runtime.h>

#define N_NODES 20000
#define E_EDGES 640000
#define F_DIM 128
#define RBF_DIM 64
#define T_TYPES 5
#define NSEG (N_NODES * T_TYPES)

typedef __attribute__((ext_vector_type(8))) short short8;
typedef __attribute__((ext_vector_type(4))) float f32x4;

__device__ __forceinline__ float silu_f(float x) { return x / (1.0f + __expf(-x)); }

__device__ __forceinline__ ushort f2bf(float f) {
  unsigned u = __float_as_uint(f);
  u += 0x7fffu + ((u >> 16) & 1u);
  return (ushort)(u >> 16);
}
__device__ __forceinline__ float bf2f(ushort u) {
  return __uint_as_float(((unsigned)u) << 16);
}

// ---------------- weight prep: fp32 -> bf16 (w1,w2,qw,kw,vw) ----------------
__global__ __launch_bounds__(256) void prep_kernel(
    const float* __restrict__ w1, const float* __restrict__ w2,
    const float* __restrict__ qw, const float* __restrict__ kw,
    const float* __restrict__ vw, ushort* __restrict__ w1b,
    ushort* __restrict__ w2b, ushort* __restrict__ qwb,
    ushort* __restrict__ kwb, ushort* __restrict__ vwb) {
  int i = blockIdx.x * 256 + threadIdx.x;
  if (i < F_DIM * RBF_DIM) w1b[i] = f2bf(w1[i]);
  if (i < F_DIM * F_DIM) {
    w2b[i] = f2bf(w2[i]);
    qwb[i] = f2bf(qw[i]);
    kwb[i] = f2bf(kw[i]);
    vwb[i] = f2bf(vw[i]);
  }
}

// ---------------- sort by segment: hist / scan / scatter ----------------
__global__ __launch_bounds__(256) void hist_kernel(const int* __restrict__ srcp,
                                                   const int* __restrict__ dstp,
                                                   const int* __restrict__ z,
                                                   int* __restrict__ hist) {
  int e = blockIdx.x * 256 + threadIdx.x;
  int s = srcp[e];
  int seg = dstp[e] * T_TYPES + z[s];
  atomicAdd(&hist[seg], 1);
}

__global__ __launch_bounds__(256) void scan1_kernel(const int* __restrict__ hist,
                                                    int* __restrict__ offs,
                                                    int* __restrict__ bsums) {
  __shared__ int lds[256];
  int tid = threadIdx.x;
  int base = blockIdx.x * 1024 + tid * 4;
  int v[4];
  int s = 0;
#pragma unroll
  for (int i = 0; i < 4; ++i) {
    v[i] = (base + i < NSEG) ? hist[base + i] : 0;
    s += v[i];
  }
  lds[tid] = s;
  __syncthreads();
  for (int d = 1; d < 256; d <<= 1) {
    int t = (tid >= d) ? lds[tid - d] : 0;
    __syncthreads();
    lds[tid] += t;
    __syncthreads();
  }
  int excl = lds[tid] - s;
#pragma unroll
  for (int i = 0; i < 4; ++i) {
    if (base + i < NSEG) offs[base + i] = excl;
    excl += v[i];
  }
  if (tid == 255) bsums[blockIdx.x] = lds[255];
}

__global__ __launch_bounds__(128) void scan2_kernel(int* __restrict__ bsums,
                                                    int nb) {
  __shared__ int lds[128];
  int tid = threadIdx.x;
  int v = (tid < nb) ? bsums[tid] : 0;
  lds[tid] = v;
  __syncthreads();
  for (int d = 1; d < 128; d <<= 1) {
    int t = (tid >= d) ? lds[tid - d] : 0;
    __syncthreads();
    lds[tid] += t;
    __syncthreads();
  }
  if (tid < nb) bsums[tid] = lds[tid] - v;
}

__global__ __launch_bounds__(256) void scan3_kernel(const int* __restrict__ offs,
                                                    const int* __restrict__ bsums,
                                                    int* __restrict__ cursor) {
  int tid = threadIdx.x;
  int base = blockIdx.x * 1024 + tid * 4;
  int add = bsums[blockIdx.x];
#pragma unroll
  for (int i = 0; i < 4; ++i)
    if (base + i < NSEG) cursor[base + i] = offs[base + i] + add;
}

__global__ __launch_bounds__(256) void scatter_kernel(const int* __restrict__ srcp,
                                                      const int* __restrict__ dstp,
                                                      const int* __restrict__ z,
                                                      int* __restrict__ cursor,
                                                      int* __restrict__ perm) {
  int e = blockIdx.x * 256 + threadIdx.x;
  int s = srcp[e];
  int seg = dstp[e] * T_TYPES + z[s];
  int pos = atomicAdd(&cursor[seg], 1);
  perm[pos] = e;
}

// ---------------- xl = x @ lin1_w^T ----------------
__global__ __launch_bounds__(128) void lin1_kernel(const float* __restrict__ x,
                                                   const float* __restrict__ w,
                                                   float* __restrict__ xl) {
  __shared__ float xs[8 * 128];
  int tid = threadIdx.x;
  int n0 = blockIdx.x * 8;
  const float4* xg = (const float4*)(x + (size_t)n0 * 128);
  float4* xs4 = (float4*)xs;
  for (int i = tid; i < 256; i += 128) xs4[i] = xg[i];
  __syncthreads();
  int f = tid;
  float acc[8] = {};
  const float4* w4 = (const float4*)(w + (size_t)f * 128);
  for (int j4 = 0; j4 < 32; ++j4) {
    float4 wv = w4[j4];
#pragma unroll
    for (int n = 0; n < 8; ++n) {
      float4 xv = xs4[n * 32 + j4];
      acc[n] += wv.x * xv.x + wv.y * xv.y + wv.z * xv.z + wv.w * xv.w;
    }
  }
  for (int n = 0; n < 8; ++n) xl[(size_t)(n0 + n) * 128 + f] = acc[n];
}

// ---------------- per-edge filter net (MFMA, sorted) + run-reduced scatter ----
__global__ __launch_bounds__(256, 3) void edge_mfma_kernel(
    const float* __restrict__ edge_attr, const int* __restrict__ srcp,
    const int* __restrict__ dstp, const float* __restrict__ ewp,
    const int* __restrict__ z, const int* __restrict__ perm,
    const ushort* __restrict__ w1b, const float* __restrict__ b1,
    const ushort* __restrict__ w2b, const float* __restrict__ b2,
    const float* __restrict__ xl, float* __restrict__ y) {
  __shared__ ushort hs[128 * 128];  // bf16 h (swizzled) -> later msg (linear)
  __shared__ float sC[128];
  __shared__ int ssrc[128];
  __shared__ int sseg[128];
  __shared__ int sperm[128];
  __shared__ float sb1[128];
  __shared__ float sb2[128];

  const int tid = threadIdx.x;
  const int e0 = blockIdx.x * 128;
  const int lane = tid & 63;
  const int w = tid >> 6;
  const int wm = w >> 1, wn = w & 1;
  const int lr = lane & 15, lh = lane >> 4;

  if (tid < 128) {
    int e = perm[e0 + tid];
    sperm[tid] = e;
    int s = srcp[e];
    ssrc[tid] = s;
    sseg[tid] = dstp[e] * T_TYPES + z[s];
    float wd = ewp[e];
    float c = 0.5f * (__cosf(wd * 0.6283185307179586f) + 1.0f);
    sC[tid] = (wd < 5.0f) ? c : 0.0f;
    sb1[tid] = b1[tid];
    sb2[tid] = b2[tid];
  }
  __syncthreads();

  // ---- GEMM1: h = silu(EA[perm] @ w1^T + b1) -> swizzled LDS bf16 ----
  {
    f32x4 acc[4][4] = {};
#pragma unroll
    for (int ks = 0; ks < 2; ++ks) {
      const int k0 = ks * 32;
      short8 af[4], bfr[4];
#pragma unroll
      for (int fm = 0; fm < 4; ++fm) {
        int erow = sperm[wm * 64 + fm * 16 + lr];
        const float* ap = edge_attr + (size_t)erow * 64 + k0 + lh * 8;
        float4 a0 = *(const float4*)ap;
        float4 a1 = *(const float4*)(ap + 4);
        short8 t;
        t[0] = (short)f2bf(a0.x); t[1] = (short)f2bf(a0.y);
        t[2] = (short)f2bf(a0.z); t[3] = (short)f2bf(a0.w);
        t[4] = (short)f2bf(a1.x); t[5] = (short)f2bf(a1.y);
        t[6] = (short)f2bf(a1.z); t[7] = (short)f2bf(a1.w);
        af[fm] = t;
      }
#pragma unroll
      for (int fc = 0; fc < 4; ++fc)
        bfr[fc] = *(const short8*)(w1b + (size_t)(wn * 64 + fc * 16 + lr) * 64 +
                                   k0 + lh * 8);
#pragma unroll
      for (int fm = 0; fm < 4; ++fm)
#pragma unroll
        for (int fc = 0; fc < 4; ++fc)
          acc[fm][fc] = __builtin_amdgcn_mfma_f32_16x16x32_bf16(
              af[fm], bfr[fc], acc[fm][fc], 0, 0, 0);
    }
#pragma unroll
    for (int fm = 0; fm < 4; ++fm) {
#pragma unroll
      for (int fc = 0; fc < 4; ++fc) {
#pragma unroll
        for (int r = 0; r < 4; ++r) {
          int ml = wm * 64 + fm * 16 + lh * 4 + r;
          int n = wn * 64 + fc * 16 + lr;
          float hv = silu_f(acc[fm][fc][r] + sb1[n]);
          int byte_in_row = (n * 2) ^ ((ml & 7) << 4);
          hs[(ml * 256 + byte_in_row) >> 1] = f2bf(hv);
        }
      }
    }
  }
  __syncthreads();

  // ---- GEMM2: W = h @ w2^T + b2 ----
  f32x4 acc2[4][4] = {};
#pragma unroll
  for (int ks = 0; ks < 4; ++ks) {
    const int k0 = ks * 32;
    short8 af[4], bfr[4];
#pragma unroll
    for (int fm = 0; fm < 4; ++fm) {
      int ml = wm * 64 + fm * 16 + lr;
      int byte_in_row = (k0 * 2 + lh * 16) ^ ((ml & 7) << 4);
      af[fm] = *(const short8*)&hs[(ml * 256 + byte_in_row) >> 1];
    }
#pragma unroll
    for (int fc = 0; fc < 4; ++fc)
      bfr[fc] = *(const short8*)(w2b + (size_t)(wn * 64 + fc * 16 + lr) * 128 +
                                 k0 + lh * 8);
#pragma unroll
    for (int fm = 0; fm < 4; ++fm)
#pragma unroll
      for (int fc = 0; fc < 4; ++fc)
        acc2[fm][fc] = __builtin_amdgcn_mfma_f32_16x16x32_bf16(
            af[fm], bfr[fc], acc2[fm][fc], 0, 0, 0);
  }
  __syncthreads();  // all hs reads done

  // msg = (W + b2) * C * xl[src] -> linear LDS bf16
#pragma unroll
  for (int fm = 0; fm < 4; ++fm) {
#pragma unroll
    for (int r = 0; r < 4; ++r) {
      int ml = wm * 64 + fm * 16 + lh * 4 + r;
      float c = sC[ml];
      const float* xlr = xl + (size_t)ssrc[ml] * 128;
#pragma unroll
      for (int fc = 0; fc < 4; ++fc) {
        int n = wn * 64 + fc * 16 + lr;
        float val = (acc2[fm][fc][r] + sb2[n]) * c * xlr[n];
        hs[ml * 128 + n] = f2bf(val);
      }
    }
  }
  __syncthreads();

  // run-walk: rows sorted by seg -> one atomic per (run, col)
  {
    int col = tid & 127;
    int r0 = (tid >> 7) * 64;
    float acc = 0.0f;
    int cur = sseg[r0];
    for (int r = r0; r < r0 + 64; ++r) {
      int sg = sseg[r];
      float v = bf2f(hs[r * 128 + col]);
      if (sg != cur) {
        atomicAdd(&y[(size_t)cur * 128 + col], acc);
        acc = 0.0f;
        cur = sg;
      }
      acc += v;
    }
    atomicAdd(&y[(size_t)cur * 128 + col], acc);
  }
}

// ---------------- fused qkv (MFMA) + attention + slot-sum ----------------
#define QS 132  // padded LDS row stride (ushorts)
__global__ __launch_bounds__(256) void attn_fused_kernel(
    const float* __restrict__ y, const int* __restrict__ hist,
    const ushort* __restrict__ qwb, const ushort* __restrict__ kwb,
    const ushort* __restrict__ vwb, const float* __restrict__ qb,
    const float* __restrict__ kb, const float* __restrict__ vb,
    float* __restrict__ sout) {
  __shared__ ushort qs[160 * QS];
  __shared__ ushort ks_[160 * QS];
  __shared__ ushort vs[160 * QS];
  __shared__ float aa[32 * 8 * 5];
  __shared__ float pmv[160];
  __shared__ float sxb[3][128];

  const int tid = threadIdx.x;
  const int n0 = blockIdx.x * 32;
  const int row0 = n0 * T_TYPES;
  const int lane = tid & 63;
  const int w = tid >> 6;
  const int wm = w >> 1, wn = w & 1;
  const int lr = lane & 15, lh = lane >> 4;

  if (tid < 128) {
    sxb[0][tid] = qb[tid];
    sxb[1][tid] = kb[tid];
    sxb[2][tid] = vb[tid];
  }
  if (tid < 160) pmv[tid] = (hist[(size_t)row0 + tid] > 0) ? 1.0f : 0.0f;

  // load all A fragments (y rows, fp32 -> bf16), reused across q/k/v
  short8 A[4][5];
#pragma unroll
  for (int ksi = 0; ksi < 4; ++ksi) {
#pragma unroll
    for (int fm = 0; fm < 5; ++fm) {
      const float* ap =
          y + (size_t)(row0 + wm * 80 + fm * 16 + lr) * 128 + ksi * 32 + lh * 8;
      float4 a0 = *(const float4*)ap;
      float4 a1 = *(const float4*)(ap + 4);
      short8 t;
      t[0] = (short)f2bf(a0.x); t[1] = (short)f2bf(a0.y);
      t[2] = (short)f2bf(a0.z); t[3] = (short)f2bf(a0.w);
      t[4] = (short)f2bf(a1.x); t[5] = (short)f2bf(a1.y);
      t[6] = (short)f2bf(a1.z); t[7] = (short)f2bf(a1.w);
      A[ksi][fm] = t;
    }
  }
  __syncthreads();  // biases/pmv staged

  const ushort* Wp[3] = {qwb, kwb, vwb};
  ushort* Xp[3] = {qs, ks_, vs};
#pragma unroll
  for (int m = 0; m < 3; ++m) {
    f32x4 acc[5][4] = {};
#pragma unroll
    for (int ksi = 0; ksi < 4; ++ksi) {
      short8 B[4];
#pragma unroll
      for (int fc = 0; fc < 4; ++fc)
        B[fc] = *(const short8*)(Wp[m] + (size_t)(wn * 64 + fc * 16 + lr) * 128 +
                                 ksi * 32 + lh * 8);
#pragma unroll
      for (int fm = 0; fm < 5; ++fm)
#pragma unroll
        for (int fc = 0; fc < 4; ++fc)
          acc[fm][fc] = __builtin_amdgcn_mfma_f32_16x16x32_bf16(
              A[ksi][fm], B[fc], acc[fm][fc], 0, 0, 0);
    }
#pragma unroll
    for (int fm = 0; fm < 5; ++fm)
#pragma unroll
      for (int fc = 0; fc < 4; ++fc)
#pragma unroll
        for (int r = 0; r < 4; ++r) {
          int rrow = wm * 80 + fm * 16 + lh * 4 + r;
          int col = wn * 64 + fc * 16 + lr;
          Xp[m][rrow * QS + col] = f2bf(acc[fm][fc][r] + sxb[m][col]);
        }
  }
  __syncthreads();

  // attention scores: thread -> (n, h)
  {
    int n = tid >> 3, h = tid & 7;
    float kv[5][16];
#pragma unroll
    for (int j = 0; j < 5; ++j)
#pragma unroll
      for (int d = 0; d < 16; ++d)
        kv[j][d] = bf2f(ks_[(n * 5 + j) * QS + h * 16 + d]);
    float a[5] = {};
    for (int i = 0; i < 5; ++i) {
      float qv[16];
#pragma unroll
      for (int d = 0; d < 16; ++d)
        qv[d] = bf2f(qs[(n * 5 + i) * QS + h * 16 + d]);
      float pmi = pmv[n * 5 + i];
#pragma unroll
      for (int j = 0; j < 5; ++j) {
        float dd = 0.0f;
#pragma unroll
        for (int d = 0; d < 16; ++d) dd += qv[d] * kv[j][d];
        a[j] += pmi * silu_f(dd);
      }
    }
#pragma unroll
    for (int j = 0; j < 5; ++j) aa[(n * 8 + h) * 5 + j] = a[j] * pmv[n * 5 + j];
  }
  __syncthreads();

  // s[n][f] = sum_j aa[n][h(f)][j] * v[n][j][f]
  {
    int f = tid & 127, g2 = tid >> 7;
    int h = f >> 4;
    for (int k = 0; k < 16; ++k) {
      int n = g2 * 16 + k;
      float acc = 0.0f;
#pragma unroll
      for (int j = 0; j < 5; ++j)
        acc += aa[(n * 8 + h) * 5 + j] * bf2f(vs[(n * 5 + j) * QS + f]);
      sout[(size_t)(n0 + n) * 128 + f] = acc;
    }
  }
}

// ---------------- out = silu((s@o1^T + npm*o1_b) @ o2^T + o2_b) ----------------
__global__ __launch_bounds__(128) void out_kernel(
    const float* __restrict__ sbufg, const int* __restrict__ hist,
    const float* __restrict__ o1w, const float* __restrict__ o1b,
    const float* __restrict__ o2w, const float* __restrict__ o2b,
    float* __restrict__ outp) {
  __shared__ float sb[8 * 128];
  __shared__ float t1[8 * 128];
  __shared__ float npm[8];
  int tid = threadIdx.x;
  int n0 = blockIdx.x * 8;
  const float4* sg4 = (const float4*)(sbufg + (size_t)n0 * 128);
  float4* sb4 = (float4*)sb;
  for (int i = tid; i < 256; i += 128) sb4[i] = sg4[i];
  if (tid < 8) {
    float s = 0.0f;
    for (int t = 0; t < T_TYPES; ++t)
      s += (hist[(size_t)(n0 + tid) * T_TYPES + t] > 0) ? 1.0f : 0.0f;
    npm[tid] = s;
  }
  __syncthreads();
  int f = tid;
  {
    const float4* wg = (const float4*)(o1w + (size_t)f * 128);
    float acc[8] = {};
    for (int j4 = 0; j4 < 32; ++j4) {
      float4 wv = wg[j4];
#pragma unroll
      for (int n = 0; n < 8; ++n) {
        float4 sv = sb4[n * 32 + j4];
        acc[n] += wv.x * sv.x + wv.y * sv.y + wv.z * sv.z + wv.w * sv.w;
      }
    }
    float bb = o1b[f];
    for (int n = 0; n < 8; ++n) t1[n * 128 + f] = acc[n] + npm[n] * bb;
  }
  __syncthreads();
  {
    const float4* wg = (const float4*)(o2w + (size_t)f * 128);
    const float4* t14 = (const float4*)t1;
    float acc[8] = {};
    for (int j4 = 0; j4 < 32; ++j4) {
      float4 wv = wg[j4];
#pragma unroll
      for (int n = 0; n < 8; ++n) {
        float4 tv = t14[n * 32 + j4];
        acc[n] += wv.x * tv.x + wv.y * tv.y + wv.z * tv.z + wv.w * tv.w;
      }
    }
    float bb = o2b[f];
    for (int n = 0; n < 8; ++n) outp[(size_t)(n0 + n) * 128 + f] = silu_f(acc[n] + bb);
  }
}

extern "C" void kernel_launch(void* const* d_in, const int* in_sizes, int n_in,
                              void* d_out, int out_size, void* d_ws, size_t ws_size,
                              hipStream_t stream) {
  const float* x = (const float*)d_in[0];
  const int* z = (const int*)d_in[1];
  const int* ei = (const int*)d_in[2];
  const float* ew = (const float*)d_in[3];
  const float* ea = (const float*)d_in[4];
  const float* lin1_w = (const float*)d_in[5];
  const float* fw1 = (const float*)d_in[6];
  const float* fb1 = (const float*)d_in[7];
  const float* fw2 = (const float*)d_in[8];
  const float* fb2 = (const float*)d_in[9];
  const float* qw = (const float*)d_in[10];
  const float* qb = (const float*)d_in[11];
  const float* kw = (const float*)d_in[12];
  const float* kb = (const float*)d_in[13];
  const float* vw = (const float*)d_in[14];
  const float* vb = (const float*)d_in[15];
  const float* o1w = (const float*)d_in[16];
  const float* o1b = (const float*)d_in[17];
  const float* o2w = (const float*)d_in[18];
  const float* o2b = (const float*)d_in[19];
  float* outp = (float*)d_out;
  float* ws = (float*)d_ws;

  float* xl = ws;                           // N*F  (aliased by sbuf later)
  float* sbuf = xl;                         // alias: xl dead after edge kernel
  float* y = xl + (size_t)N_NODES * F_DIM;  // N*T*F
  ushort* w1b = (ushort*)(y + (size_t)NSEG * F_DIM);
  ushort* w2b = w1b + F_DIM * RBF_DIM;
  ushort* qwb = w2b + F_DIM * F_DIM;
  ushort* kwb = qwb + F_DIM * F_DIM;
  ushort* vwb = kwb + F_DIM * F_DIM;
  int* hist = (int*)(vwb + F_DIM * F_DIM);
  int* offs = hist + NSEG;
  int* cursor = offs + NSEG;
  int* bsums = cursor + NSEG;
  int* perm = bsums + 128;

  const int* srcp = ei;
  const int* dstp = ei + E_EDGES;
  const int NB_SCAN = (NSEG + 1023) / 1024;  // 98

  hipMemsetAsync(y, 0, (size_t)NSEG * F_DIM * sizeof(float), stream);
  hipMemsetAsync(hist, 0, (size_t)NSEG * sizeof(int), stream);

  prep_kernel<<<64, 256, 0, stream>>>(fw1, fw2, qw, kw, vw, w1b, w2b, qwb, kwb, vwb);
  hist_kernel<<<E_EDGES / 256, 256, 0, stream>>>(srcp, dstp, z, hist);
  scan1_kernel<<<NB_SCAN, 256, 0, stream>>>(hist, offs, bsums);
  scan2_kernel<<<1, 128, 0, stream>>>(bsums, NB_SCAN);
  scan3_kernel<<<NB_SCAN, 256, 0, stream>>>(offs, bsums, cursor);
  scatter_kernel<<<E_EDGES / 256, 256, 0, stream>>>(srcp, dstp, z, cursor, perm);
  lin1_kernel<<<N_NODES / 8, 128, 0, stream>>>(x, lin1_w, xl);
  edge_mfma_kernel<<<E_EDGES / 128, 256, 0, stream>>>(ea, srcp, dstp, ew, z, perm,
                                                      w1b, fb1, w2b, fb2, xl, y);
  attn_fused_kernel<<<N_NODES / 32, 256, 0, stream>>>(y, hist, qwb, kwb, vwb, qb,
                                                      kb, vb, sbuf);
  out_kernel<<<N_NODES / 8, 128, 0, stream>>>(sbuf, hist, o1w, o1b, o2w, o2b, outp);
}